// Round 1
// baseline (1397.097 us; speedup 1.0000x reference)
//
#include <hip/hip_runtime.h>
#include <hip/hip_bf16.h>

// ---------------------------------------------------------------------------
// NodeBlock: out = relu([seg_mean(edge_attrs,dst), node_attrs, g] @ W1 + b1) @ W2 + b2
// Strategy:
//   1) counting-sort edges by dst -> CSR (count, scan, scatter ids)
//   2) gather-mean per node (coalesced 512B edge-row reads, no fp32 atomics)
//   3) fused MLP with bf16 MFMA (16x16x32); global-attr part of W1 folded
//      into a per-output bias gvec = g @ W1[256:384] + b1 (fp32, precomputed)
// ---------------------------------------------------------------------------

typedef __bf16 bf16x8 __attribute__((ext_vector_type(8)));
typedef float f32x4 __attribute__((ext_vector_type(4)));
typedef unsigned short ushort4v __attribute__((ext_vector_type(4)));

__device__ inline unsigned short f2bf(float f) {
    unsigned int u = __float_as_uint(f);
    u = u + 0x7fffu + ((u >> 16) & 1u);   // round-to-nearest-even
    return (unsigned short)(u >> 16);
}

// ---------------- pass 1: count edges per node -----------------------------
__global__ __launch_bounds__(256) void count_kernel(const int* __restrict__ dst,
                                                    int* __restrict__ cnt, int E) {
    int e = blockIdx.x * 256 + threadIdx.x;
    if (e < E) atomicAdd(&cnt[dst[e]], 1);
}

// ---------------- pass 2: exclusive scan (single block, shfl-based) --------
__global__ __launch_bounds__(1024) void scan_kernel(const int* __restrict__ cnt,
                                                    int* __restrict__ offs,
                                                    int* __restrict__ cursor, int n) {
    __shared__ int wsum[17];
    __shared__ int carry;
    int tid = threadIdx.x;
    int lane = tid & 63;
    int wv = tid >> 6;   // 16 waves
    if (tid == 0) carry = 0;
    __syncthreads();
    for (int base = 0; base < n; base += 1024) {
        int idx = base + tid;
        int v = (idx < n) ? cnt[idx] : 0;
        int s = v;
        #pragma unroll
        for (int d = 1; d < 64; d <<= 1) {
            int t = __shfl_up(s, d, 64);
            if (lane >= d) s += t;
        }
        if (lane == 63) wsum[wv] = s;
        __syncthreads();
        if (tid == 0) {
            int run = 0;
            #pragma unroll
            for (int j = 0; j < 16; j++) { int t = wsum[j]; wsum[j] = run; run += t; }
            wsum[16] = run;
        }
        __syncthreads();
        int inc = s + wsum[wv];           // block-inclusive
        int exc = carry + inc - v;        // global-exclusive
        if (idx < n) { offs[idx] = exc; cursor[idx] = exc; }
        __syncthreads();
        if (tid == 0) carry += wsum[16];
        __syncthreads();
    }
}

// ---------------- pass 3: scatter edge ids into CSR ------------------------
__global__ __launch_bounds__(256) void scatter_kernel(const int* __restrict__ dst,
                                                      int* __restrict__ cursor,
                                                      int* __restrict__ eidl, int E) {
    int e = blockIdx.x * 256 + threadIdx.x;
    if (e < E) {
        int p = atomicAdd(&cursor[dst[e]], 1);
        eidl[p] = e;
    }
}

// ---------------- weight prep: transpose->bf16, fold global into bias ------
__global__ __launch_bounds__(256) void prep_kernel(const float* __restrict__ W1,
                                                   const float* __restrict__ b1,
                                                   const float* __restrict__ W2,
                                                   const float* __restrict__ g,
                                                   unsigned short* __restrict__ W1t,
                                                   unsigned short* __restrict__ W2t,
                                                   float* __restrict__ gvec) {
    int tid = blockIdx.x * blockDim.x + threadIdx.x;
    int stride = gridDim.x * blockDim.x;
    // W1t[n][k] = W1[k][n], k in [0,256) (agg+node parts), bf16, row stride 256
    for (int i = tid; i < 128 * 256; i += stride) {
        int n = i >> 8, k = i & 255;
        W1t[i] = f2bf(W1[k * 128 + n]);
    }
    // W2t[n][k] = W2[k][n], bf16, row stride 128
    for (int i = tid; i < 128 * 128; i += stride) {
        int n = i >> 7, k = i & 127;
        W2t[i] = f2bf(W2[k * 128 + n]);
    }
    // gvec[n] = b1[n] + sum_k g[k] * W1[256+k][n]   (fp32, exact part)
    if (tid < 128) {
        float s = b1[tid];
        for (int k = 0; k < 128; k++) s += g[k] * W1[(256 + k) * 128 + tid];
        gvec[tid] = s;
    }
}

// ---------------- pass 4: gather-mean per node -----------------------------
// thread = (node, float4 chunk c of 32). 32 lanes of a node read one 512B edge
// row fully coalesced.
__global__ __launch_bounds__(256) void gather_kernel(const float* __restrict__ edge_attrs,
                                                     const int* __restrict__ eidl,
                                                     const int* __restrict__ offs,
                                                     const int* __restrict__ cnt,
                                                     float* __restrict__ agg, int n_nodes) {
    int gid = blockIdx.x * 256 + threadIdx.x;
    int n = gid >> 5, c = gid & 31;
    if (n >= n_nodes) return;
    int off = offs[n];
    int deg = cnt[n];
    const float4* ea = (const float4*)edge_attrs;
    float ax = 0.f, ay = 0.f, az = 0.f, aw = 0.f;
    int i = 0;
    for (; i + 4 <= deg; i += 4) {
        int e0 = eidl[off + i], e1 = eidl[off + i + 1];
        int e2 = eidl[off + i + 2], e3 = eidl[off + i + 3];
        float4 v0 = ea[e0 * 32 + c], v1 = ea[e1 * 32 + c];
        float4 v2 = ea[e2 * 32 + c], v3 = ea[e3 * 32 + c];
        ax += v0.x + v1.x + v2.x + v3.x;
        ay += v0.y + v1.y + v2.y + v3.y;
        az += v0.z + v1.z + v2.z + v3.z;
        aw += v0.w + v1.w + v2.w + v3.w;
    }
    for (; i < deg; i++) {
        int e = eidl[off + i];
        float4 v = ea[e * 32 + c];
        ax += v.x; ay += v.y; az += v.z; aw += v.w;
    }
    float inv = 1.0f / fmaxf((float)deg, 1.0f);
    float4 r; r.x = ax * inv; r.y = ay * inv; r.z = az * inv; r.w = aw * inv;
    ((float4*)agg)[n * 32 + c] = r;
}

// ---------------- pass 5: fused MLP with bf16 MFMA -------------------------
// Block: 256 threads = 4 waves, 64 nodes. Wave w owns node rows [w*16, w*16+16).
// GEMM1: [64 x 256] @ [256 x 128] -> relu(+gvec) -> GEMM2: [64 x 128] @ [128 x 128]
#define LDH 264   // 256 + 8 pad (ushort) -> 528B rows, 16B aligned, 2-way bank alias
#define LDY 136   // 128 + 8 pad (ushort) -> 272B rows
__global__ __launch_bounds__(256) void mlp_kernel(const float* __restrict__ agg,
                                                  const float* __restrict__ node_attrs,
                                                  const unsigned short* __restrict__ W1t,
                                                  const unsigned short* __restrict__ W2t,
                                                  const float* __restrict__ gvec,
                                                  const float* __restrict__ b2,
                                                  float* __restrict__ out, int n_nodes) {
    __shared__ unsigned short lds_h[64 * LDH];
    __shared__ unsigned short lds_y[64 * LDY];
    int tid = threadIdx.x;
    int n0 = blockIdx.x * 64;

    // stage h = [agg | node_attrs] as bf16 (64 rows x 256 cols)
    for (int i = tid; i < 64 * 64; i += 256) {
        int r = i >> 6, c4 = i & 63;    // c4 indexes float4 chunks over 256 cols
        int node = n0 + r;
        float4 v; v.x = 0.f; v.y = 0.f; v.z = 0.f; v.w = 0.f;
        if (node < n_nodes) {
            if (c4 < 32) v = ((const float4*)agg)[node * 32 + c4];
            else         v = ((const float4*)node_attrs)[node * 32 + (c4 - 32)];
        }
        int col = c4 * 4;
        ushort4v u;
        u.x = f2bf(v.x); u.y = f2bf(v.y); u.z = f2bf(v.z); u.w = f2bf(v.w);
        *(ushort4v*)(lds_h + r * LDH + col) = u;
    }
    __syncthreads();

    int lane = tid & 63;
    int w = tid >> 6;
    int lrow = lane & 15;
    int quad = lane >> 4;
    int m = w * 16 + lrow;   // A-fragment row (node within tile)

    f32x4 acc[8];
    #pragma unroll
    for (int i = 0; i < 8; i++) acc[i] = (f32x4){0.f, 0.f, 0.f, 0.f};

    // GEMM1: K = 256 (8 steps of 32)
    #pragma unroll
    for (int ks = 0; ks < 8; ks++) {
        bf16x8 a = *(const bf16x8*)(lds_h + m * LDH + ks * 32 + quad * 8);
        const unsigned short* bp = W1t + lrow * 256 + ks * 32 + quad * 8;
        #pragma unroll
        for (int nb = 0; nb < 8; nb++) {
            bf16x8 b = *(const bf16x8*)(bp + nb * 16 * 256);
            acc[nb] = __builtin_amdgcn_mfma_f32_16x16x32_bf16(a, b, acc[nb], 0, 0, 0);
        }
    }

    // relu(acc + gvec) -> lds_y (bf16), C layout: row = w*16+quad*4+reg, col = nb*16+lrow
    #pragma unroll
    for (int nb = 0; nb < 8; nb++) {
        int n = nb * 16 + lrow;
        float gv = gvec[n];
        #pragma unroll
        for (int reg = 0; reg < 4; reg++) {
            int row = w * 16 + quad * 4 + reg;
            float y = fmaxf(acc[nb][reg] + gv, 0.f);
            lds_y[row * LDY + n] = f2bf(y);
        }
    }
    __syncthreads();

    f32x4 acc2[8];
    #pragma unroll
    for (int i = 0; i < 8; i++) acc2[i] = (f32x4){0.f, 0.f, 0.f, 0.f};

    // GEMM2: K = 128 (4 steps of 32)
    #pragma unroll
    for (int ks = 0; ks < 4; ks++) {
        bf16x8 a = *(const bf16x8*)(lds_y + m * LDY + ks * 32 + quad * 8);
        const unsigned short* bp = W2t + lrow * 128 + ks * 32 + quad * 8;
        #pragma unroll
        for (int nb = 0; nb < 8; nb++) {
            bf16x8 b = *(const bf16x8*)(bp + nb * 16 * 128);
            acc2[nb] = __builtin_amdgcn_mfma_f32_16x16x32_bf16(a, b, acc2[nb], 0, 0, 0);
        }
    }

    // epilogue: out = acc2 + b2
    #pragma unroll
    for (int nb = 0; nb < 8; nb++) {
        int n = nb * 16 + lrow;
        float bb = b2[n];
        #pragma unroll
        for (int reg = 0; reg < 4; reg++) {
            int row = w * 16 + quad * 4 + reg;
            int node = n0 + row;
            if (node < n_nodes) out[node * 128 + n] = acc2[nb][reg] + bb;
        }
    }
}

// ---------------------------------------------------------------------------
extern "C" void kernel_launch(void* const* d_in, const int* in_sizes, int n_in,
                              void* d_out, int out_size, void* d_ws, size_t ws_size,
                              hipStream_t stream) {
    const float* edge_attrs  = (const float*)d_in[0];
    const float* node_attrs  = (const float*)d_in[1];
    const float* global_attr = (const float*)d_in[2];
    const float* W1 = (const float*)d_in[3];
    const float* b1 = (const float*)d_in[4];
    const float* W2 = (const float*)d_in[5];
    const float* b2 = (const float*)d_in[6];
    const int* edge_dst = (const int*)d_in[7];

    int E = in_sizes[0] / 128;
    int N = in_sizes[1] / 128;

    char* ws = (char*)d_ws;
    int* cnt    = (int*)ws;                       // N ints (200 KB)
    int* offs   = (int*)(ws + 0x40000);           // N ints
    int* cursor = (int*)(ws + 0x80000);           // N ints
    int* eidl   = (int*)(ws + 0xC0000);           // E ints (6.4 MB)
    unsigned short* W1t = (unsigned short*)(ws + 0x800000);  // 64 KB
    unsigned short* W2t = (unsigned short*)(ws + 0x810000);  // 32 KB
    float* gvec = (float*)(ws + 0x818000);        // 512 B

    float* agg = (float*)d_out;   // reuse output buffer for the [N,128] means
    float* out = (float*)d_out;

    hipMemsetAsync(cnt, 0, N * sizeof(int), stream);
    count_kernel<<<(E + 255) / 256, 256, 0, stream>>>(edge_dst, cnt, E);
    scan_kernel<<<1, 1024, 0, stream>>>(cnt, offs, cursor, N);
    scatter_kernel<<<(E + 255) / 256, 256, 0, stream>>>(edge_dst, cursor, eidl, E);
    prep_kernel<<<64, 256, 0, stream>>>(W1, b1, W2, global_attr, W1t, W2t, gvec);
    gather_kernel<<<(N * 32 + 255) / 256, 256, 0, stream>>>(edge_attrs, eidl, offs, cnt, agg, N);
    mlp_kernel<<<(N + 63) / 64, 256, 0, stream>>>(agg, node_attrs, W1t, W2t, gvec, b2, out, N);
}